// Round 10
// baseline (135.981 us; speedup 1.0000x reference)
//
#include <hip/hip_runtime.h>
#include <stdint.h>
#include <math.h>

#define BH_ 16
#define N_  2048
#define D_  64
#define NEGV (-1e15f)

typedef __attribute__((ext_vector_type(8))) short bf16x8;
typedef __attribute__((ext_vector_type(8))) unsigned short us8;
typedef __attribute__((ext_vector_type(4))) float f32x4;

// ---------------- workspace layout ----------------
#define OFF_MASKU8 0u
#define OFF_MBITS  32768u                // 16*32 u64
#define OFF_EBITS  65536u                // 2*2048*128 u16 = 1 MB
#define OFF_QBF    1114112u              // 4 MB bf16
#define OFF_KBF    5308416u              // 4 MB
#define OFF_VT     9502720u              // 4 MB (transposed [bh][d][n])
#define WS_V6      13697024u
#define OFF_PSUM   13697024u             // 16*2048*4 f32 = 512 KB
#define OFF_OPART  14221312u             // 2*16*2048*64 f32 = 16.8 MB
#define WS_V7      30998528u

// Barrier WITHOUT the implicit vmcnt(0) drain of __syncthreads: LDS visibility
// only (lgkmcnt). Global stores/loads stay in flight across it.
#define BARRIER_LGKM() do {                                   \
    asm volatile("s_waitcnt lgkmcnt(0)" ::: "memory");        \
    __builtin_amdgcn_sched_barrier(0);                        \
    __builtin_amdgcn_s_barrier();                             \
    __builtin_amdgcn_sched_barrier(0);                        \
} while (0)

__device__ __forceinline__ unsigned short f2bf(float f) {
    unsigned u = __float_as_uint(f);
    return (unsigned short)((u + 0x7FFFu + ((u >> 16) & 1u)) >> 16);   // RNE
}

// ---- fused prepass: edge pack (blocks 0..2047), q/k/v convert (2048..2559),
//      mask pack+detect (2560..2575)
__global__ __launch_bounds__(256)
void prep_all(const float* __restrict__ q, const float* __restrict__ k,
              const float* __restrict__ v, const void* __restrict__ mraw,
              const int* __restrict__ edge,
              unsigned short* __restrict__ qbf, unsigned short* __restrict__ kbf,
              unsigned short* __restrict__ vT,
              unsigned short* __restrict__ e16, unsigned long long* __restrict__ mbits)
{
    __shared__ unsigned short shbuf[64][72];
    __shared__ int flag;
    const int bid = blockIdx.x;
    const int t   = threadIdx.x;

    if (bid < 2048) {               // ---- edge -> u16 bitmasks (thread-local)
        const int idx = bid * 256 + t;            // 0..524287
        const int4* p = (const int4*)(edge + (size_t)idx * 16);
        unsigned m = 0;
        #pragma unroll
        for (int i = 0; i < 4; ++i) {
            const int4 vv = p[i];
            m |= (vv.x != 0 ? 1u : 0u) << (i * 4 + 0);
            m |= (vv.y != 0 ? 1u : 0u) << (i * 4 + 1);
            m |= (vv.z != 0 ? 1u : 0u) << (i * 4 + 2);
            m |= (vv.w != 0 ? 1u : 0u) << (i * 4 + 3);
        }
        e16[idx] = (unsigned short)m;
    } else if (bid < 2560) {        // ---- q,k -> bf16; v -> bf16 transposed
        const int b2 = bid - 2048;
        const int rt = b2 & 31, bh = b2 >> 5;
        const size_t base = ((size_t)bh * N_ + (size_t)rt * 64) * D_;
        #pragma unroll
        for (int i = 0; i < 4; ++i) {
            const int idx = t + i * 256;
            float4 f = *(const float4*)(q + base + (size_t)idx * 4);
            ushort4 s; s.x = f2bf(f.x); s.y = f2bf(f.y); s.z = f2bf(f.z); s.w = f2bf(f.w);
            *(ushort4*)(qbf + base + (size_t)idx * 4) = s;
            f = *(const float4*)(k + base + (size_t)idx * 4);
            s.x = f2bf(f.x); s.y = f2bf(f.y); s.z = f2bf(f.z); s.w = f2bf(f.w);
            *(ushort4*)(kbf + base + (size_t)idx * 4) = s;
            f = *(const float4*)(v + base + (size_t)idx * 4);
            const int row = idx >> 4;
            const int d0  = (idx & 15) * 4;
            shbuf[d0 + 0][row] = f2bf(f.x);
            shbuf[d0 + 1][row] = f2bf(f.y);
            shbuf[d0 + 2][row] = f2bf(f.z);
            shbuf[d0 + 3][row] = f2bf(f.w);
        }
        __syncthreads();
        const int d  = t >> 2;
        const int c4 = (t & 3) * 16;
        const size_t ob = ((size_t)bh * D_ + d) * N_ + (size_t)rt * 64 + c4;
        *(us8*)(vT + ob)     = *(us8*)&shbuf[d][c4];
        *(us8*)(vT + ob + 8) = *(us8*)&shbuf[d][c4 + 8];
    } else {                        // ---- mask detect + pack
        const int bh = bid - 2560;
        if (t == 0) flag = 0;
        __syncthreads();
        const int* mi = (const int*)mraw;
        int bad = 0;
        for (int i = t; i < 8192; i += 256)
            if ((unsigned)mi[i] > 1u) bad = 1;
        if (bad) atomicOr(&flag, 1);
        __syncthreads();
        const int is_u8 = flag;
        const uint8_t* m8 = (const uint8_t*)mraw;
        const int w4 = t >> 6, l = t & 63;
        for (int it = 0; it < 8; ++it) {
            const int pos = bh * 2048 + it * 256 + w4 * 64 + l;
            const bool on = is_u8 ? (m8[pos] != 0) : (mi[pos] != 0);
            unsigned long long bal = __ballot(on);
            if (l == 0) mbits[bh * 32 + it * 4 + w4] = bal;
        }
    }
}

// ---- v7 kernel A: partial row sums, 4-way key split. Grid (32, 16, 4).
// Block (tile, bh, s): rows tile*64..+63, chunks s*8 .. s*8+7. Per-wave
// structure identical to v6 pass 1. 16 KB LDS -> high occupancy; 8192 waves.
__global__ __launch_bounds__(256)
void attn_sumk(const unsigned short* __restrict__ qbf,
               const unsigned short* __restrict__ kbf,
               const unsigned long long* __restrict__ ebits,
               const unsigned long long* __restrict__ mbits,
               float* __restrict__ psum)
{
    __shared__ unsigned short sK[2][4096];

    const int tile = blockIdx.x, bh = blockIdx.y, s = blockIdx.z;
    const int t = threadIdx.x;
    const int w = t >> 6, lane = t & 63, l15 = lane & 15, lg = lane >> 4;
    const int rbase = tile * 64;
    const int myrow = rbase + w * 16 + l15;
    const int kcb = s * 8;

    const unsigned short* qb = qbf + (size_t)bh * N_ * D_;
    const unsigned short* kb = kbf + (size_t)bh * N_ * D_;
    const unsigned long long* ebrow =
        ebits + ((size_t)(bh & 1) * N_ + (size_t)myrow) * 32;
    const unsigned long long* mb = mbits + bh * 32;

    const bf16x8 aq0 = *(const bf16x8*)(qb + (size_t)myrow * D_ + lg * 8);
    const bf16x8 aq1 = *(const bf16x8*)(qb + (size_t)myrow * D_ + lg * 8 + 32);

    const int s0row = t >> 3, s1row = s0row + 32, t8 = t & 7;
    const int ds0 = s0row * 64 + ((t8 ^ (s0row & 7)) * 8);
    const int ds1 = s1row * 64 + ((t8 ^ (s1row & 7)) * 8);

    {
        const unsigned short* src = kb + (size_t)kcb * 4096;
        *(us8*)(sK[0] + ds0) = *(const us8*)(src + (size_t)t * 8);
        *(us8*)(sK[0] + ds1) = *(const us8*)(src + (size_t)(t + 256) * 8);
        BARRIER_LGKM();
    }
    float lacc = 0.f;
    #pragma unroll 1
    for (int i = 0; i < 8; ++i) {
        const int kc = kcb + i;
        const int cur = i & 1;
        us8 nk0, nk1;
        if (i < 7) {
            const unsigned short* src = kb + (size_t)(kc + 1) * 4096;
            nk0 = *(const us8*)(src + (size_t)t * 8);
            nk1 = *(const us8*)(src + (size_t)(t + 256) * 8);
        }
        const unsigned long long wbits = ebrow[kc] & ~mb[kc];
        const unsigned short* kcur = sK[cur];
        #pragma unroll
        for (int nt = 0; nt < 4; ++nt) {
            const int row = nt * 16 + l15, sw = row & 7;
            const bf16x8 k0 = *(const bf16x8*)(kcur + row * 64 + ((lg ^ sw) * 8));
            const bf16x8 k1 = *(const bf16x8*)(kcur + row * 64 + (((lg + 4) ^ sw) * 8));
            f32x4 c = (f32x4){0.f, 0.f, 0.f, 0.f};
            c = __builtin_amdgcn_mfma_f32_16x16x32_bf16(k0, aq0, c, 0, 0, 0);
            c = __builtin_amdgcn_mfma_f32_16x16x32_bf16(k1, aq1, c, 0, 0, 0);
            const unsigned bits = (unsigned)(wbits >> (nt * 16 + lg * 4)) & 0xFu;
            #pragma unroll
            for (int r = 0; r < 4; ++r)
                lacc += ((bits >> r) & 1u) ? __expf(c[r] * 0.125f) : 0.f;
        }
        if (i < 7) {
            *(us8*)(sK[cur ^ 1] + ds0) = nk0;
            *(us8*)(sK[cur ^ 1] + ds1) = nk1;
        }
        BARRIER_LGKM();
    }
    lacc += __shfl_xor(lacc, 16);
    lacc += __shfl_xor(lacc, 32);
    if (lane < 16) psum[((size_t)bh * N_ + myrow) * 4 + s] = lacc;
}

// ---- v7 kernel B: attn + partial PV, 2-way key split. Grid (32, 16, 2).
// Exact v6 pass-2 body; chunks s*16..s*16+15; partial o -> opart[s].
__global__ __launch_bounds__(256)
void attn_pvk(const unsigned short* __restrict__ qbf,
              const unsigned short* __restrict__ kbf,
              const unsigned short* __restrict__ vT,
              const unsigned long long* __restrict__ ebits,
              const unsigned long long* __restrict__ mbits,
              const float* __restrict__ psum,
              float* __restrict__ opart, float* __restrict__ attn)
{
    __shared__ unsigned short sK[2][4096];
    __shared__ unsigned short sV[2][4096];
    __shared__ char pbuf[4][2048];

    const int tile = blockIdx.x, bh = blockIdx.y, s = blockIdx.z;
    const int t = threadIdx.x;
    const int w = t >> 6, lane = t & 63, l15 = lane & 15, lg = lane >> 4;
    const int rbase = tile * 64;
    const int myrow = rbase + w * 16 + l15;
    const int kcb = s * 16;

    const unsigned short* qb = qbf + (size_t)bh * N_ * D_;
    const unsigned short* kb = kbf + (size_t)bh * N_ * D_;
    const unsigned short* vb = vT  + (size_t)bh * D_ * N_;
    const unsigned long long* ebrow =
        ebits + ((size_t)(bh & 1) * N_ + (size_t)myrow) * 32;
    const unsigned long long* mb = mbits + bh * 32;
    float* arow = attn + (size_t)bh * N_ * N_ + (size_t)myrow * N_ + lg * 4;

    const f32x4 ps = *(const f32x4*)(psum + ((size_t)bh * N_ + myrow) * 4);
    const float inv = 1.0f / (ps[0] + ps[1] + ps[2] + ps[3]);

    const bf16x8 aq0 = *(const bf16x8*)(qb + (size_t)myrow * D_ + lg * 8);
    const bf16x8 aq1 = *(const bf16x8*)(qb + (size_t)myrow * D_ + lg * 8 + 32);

    const int s0row = t >> 3, s1row = s0row + 32, t8 = t & 7;
    const int ds0 = s0row * 64 + ((t8 ^ (s0row & 7)) * 8);
    const int ds1 = s1row * 64 + ((t8 ^ (s1row & 7)) * 8);

    {   // prologue: stage K[kcb], V[kcb]
        const unsigned short* srck = kb + (size_t)kcb * 4096;
        const unsigned short* srcv = vb + (size_t)kcb * 64;
        *(us8*)(sK[0] + ds0) = *(const us8*)(srck + (size_t)t * 8);
        *(us8*)(sK[0] + ds1) = *(const us8*)(srck + (size_t)(t + 256) * 8);
        *(us8*)(sV[0] + ds0) = *(const us8*)(srcv + (size_t)s0row * 2048 + t8 * 8);
        *(us8*)(sV[0] + ds1) = *(const us8*)(srcv + (size_t)s1row * 2048 + t8 * 8);
        BARRIER_LGKM();
    }

    f32x4 o[4];
    #pragma unroll
    for (int nt = 0; nt < 4; ++nt) o[nt] = (f32x4){0.f, 0.f, 0.f, 0.f};

    char* pbw = pbuf[w];
    const int swzP = (l15 & 7) << 4;
    const int ab0 = (l15 * 128 + lg * 16)      ^ swzP;
    const int ab1 = (l15 * 128 + lg * 16 + 64) ^ swzP;

    #pragma unroll 1
    for (int i = 0; i < 16; ++i) {
        const int kc = kcb + i;
        const int cur = i & 1;
        us8 nk0, nk1, nv0, nv1;
        if (i < 15) {
            const unsigned short* srck = kb + (size_t)(kc + 1) * 4096;
            const unsigned short* srcv = vb + (size_t)(kc + 1) * 64;
            nk0 = *(const us8*)(srck + (size_t)t * 8);
            nk1 = *(const us8*)(srck + (size_t)(t + 256) * 8);
            nv0 = *(const us8*)(srcv + (size_t)s0row * 2048 + t8 * 8);
            nv1 = *(const us8*)(srcv + (size_t)s1row * 2048 + t8 * 8);
        }
        const unsigned long long wbits = ebrow[kc] & ~mb[kc];
        const unsigned short* kcur = sK[cur];
        float4 ev[4];
        #pragma unroll
        for (int nt = 0; nt < 4; ++nt) {
            const int row = nt * 16 + l15, sw = row & 7;
            const bf16x8 k0 = *(const bf16x8*)(kcur + row * 64 + ((lg ^ sw) * 8));
            const bf16x8 k1 = *(const bf16x8*)(kcur + row * 64 + (((lg + 4) ^ sw) * 8));
            f32x4 c = (f32x4){0.f, 0.f, 0.f, 0.f};
            c = __builtin_amdgcn_mfma_f32_16x16x32_bf16(k0, aq0, c, 0, 0, 0);
            c = __builtin_amdgcn_mfma_f32_16x16x32_bf16(k1, aq1, c, 0, 0, 0);
            const unsigned bits = (unsigned)(wbits >> (nt * 16 + lg * 4)) & 0xFu;
            float4 e;
            e.x = (bits & 1u) ? __expf(c[0] * 0.125f) * inv : 0.f;
            e.y = (bits & 2u) ? __expf(c[1] * 0.125f) * inv : 0.f;
            e.z = (bits & 4u) ? __expf(c[2] * 0.125f) * inv : 0.f;
            e.w = (bits & 8u) ? __expf(c[3] * 0.125f) * inv : 0.f;
            ev[nt] = e;
            ushort4 pe;
            pe.x = f2bf(e.x); pe.y = f2bf(e.y); pe.z = f2bf(e.z); pe.w = f2bf(e.w);
            const int wbyte = (l15 * 128 + nt * 32 + lg * 8) ^ swzP;  // XOR last
            *(ushort4*)(pbw + wbyte) = pe;
        }
        const bf16x8 ap0 = *(const bf16x8*)(pbw + ab0);
        const bf16x8 ap1 = *(const bf16x8*)(pbw + ab1);
        const unsigned short* vcur = sV[cur];
        #pragma unroll
        for (int nt = 0; nt < 4; ++nt) {
            const int row = nt * 16 + l15, sw = row & 7;   // d-row
            const bf16x8 bv0 = *(const bf16x8*)(vcur + row * 64 + ((lg ^ sw) * 8));
            const bf16x8 bv1 = *(const bf16x8*)(vcur + row * 64 + (((lg + 4) ^ sw) * 8));
            o[nt] = __builtin_amdgcn_mfma_f32_16x16x32_bf16(ap0, bv0, o[nt], 0, 0, 0);
            o[nt] = __builtin_amdgcn_mfma_f32_16x16x32_bf16(ap1, bv1, o[nt], 0, 0, 0);
        }
        {
            float* astore = arow + kc * 64;
            #pragma unroll
            for (int nt = 0; nt < 4; ++nt)
                *(float4*)(astore + nt * 16) = ev[nt];
        }
        if (i < 15) {
            *(us8*)(sK[cur ^ 1] + ds0) = nk0;
            *(us8*)(sK[cur ^ 1] + ds1) = nk1;
            *(us8*)(sV[cur ^ 1] + ds0) = nv0;
            *(us8*)(sV[cur ^ 1] + ds1) = nv1;
        }
        BARRIER_LGKM();
    }

    float* op = opart + (size_t)s * (BH_ * N_ * D_) + (size_t)bh * N_ * D_;
    #pragma unroll
    for (int nt = 0; nt < 4; ++nt)
        #pragma unroll
        for (int r = 0; r < 4; ++r)
            op[(size_t)(rbase + w * 16 + lg * 4 + r) * D_ + nt * 16 + l15] = o[nt][r];
}

// ---- v7 kernel C: out = opart[0] + opart[1]
__global__ __launch_bounds__(256)
void reduce_o(const float* __restrict__ opart, float* __restrict__ out)
{
    const float4* a = (const float4*)opart;          // 524288 float4 per slice
    const float4* b = a + 524288;
    float4* o4 = (float4*)out;
    const size_t i = (size_t)blockIdx.x * 256 + threadIdx.x;     // 0..262143
    float4 x = a[i], y = b[i];
    o4[i] = make_float4(x.x + y.x, x.y + y.y, x.z + y.z, x.w + y.w);
    const size_t j = i + 262144;
    x = a[j]; y = b[j];
    o4[j] = make_float4(x.x + y.x, x.y + y.y, x.z + y.z, x.w + y.w);
}

// ================= v6 (mid fallback, verified round 8/9) =================
__global__ __launch_bounds__(256)
void attn_v6(const unsigned short* __restrict__ qbf,
             const unsigned short* __restrict__ kbf,
             const unsigned short* __restrict__ vT,
             const unsigned long long* __restrict__ ebits,
             const unsigned long long* __restrict__ mbits,
             float* __restrict__ out, float* __restrict__ attn)
{
    __shared__ unsigned short sK[2][4096];
    __shared__ unsigned short sV[2][4096];
    __shared__ char pbuf[4][2048];

    const int tile = blockIdx.x;
    const int bh   = blockIdx.y;
    const int t    = threadIdx.x;
    const int w    = t >> 6;
    const int lane = t & 63;
    const int l15  = lane & 15;
    const int lg   = lane >> 4;
    const int rbase = tile * 64;
    const int myrow = rbase + w * 16 + l15;

    const unsigned short* qb = qbf + (size_t)bh * N_ * D_;
    const unsigned short* kb = kbf + (size_t)bh * N_ * D_;
    const unsigned short* vb = vT  + (size_t)bh * D_ * N_;
    const unsigned long long* ebrow =
        ebits + ((size_t)(bh & 1) * N_ + (size_t)myrow) * 32;
    const unsigned long long* mb = mbits + bh * 32;
    float* outb = out + (size_t)bh * N_ * D_;
    float* arow = attn + (size_t)bh * N_ * N_ + (size_t)myrow * N_ + lg * 4;

    const bf16x8 aq0 = *(const bf16x8*)(qb + (size_t)myrow * D_ + lg * 8);
    const bf16x8 aq1 = *(const bf16x8*)(qb + (size_t)myrow * D_ + lg * 8 + 32);

    const int s0row = t >> 3;
    const int s1row = s0row + 32;
    const int t8    = t & 7;
    const int ds0 = s0row * 64 + ((t8 ^ (s0row & 7)) * 8);
    const int ds1 = s1row * 64 + ((t8 ^ (s1row & 7)) * 8);

    {
        const us8 a0 = *(const us8*)(kb + (size_t)t * 8);
        const us8 a1 = *(const us8*)(kb + (size_t)(t + 256) * 8);
        *(us8*)(sK[0] + ds0) = a0;
        *(us8*)(sK[0] + ds1) = a1;
        BARRIER_LGKM();
    }
    float lacc = 0.f;
    #pragma unroll 1
    for (int kc = 0; kc < 32; ++kc) {
        const int cur = kc & 1;
        us8 nk0, nk1;
        if (kc < 31) {
            const unsigned short* s = kb + (size_t)(kc + 1) * 4096;
            nk0 = *(const us8*)(s + (size_t)t * 8);
            nk1 = *(const us8*)(s + (size_t)(t + 256) * 8);
        }
        const unsigned long long wbits = ebrow[kc] & ~mb[kc];
        const unsigned short* kcur = sK[cur];
        #pragma unroll
        for (int nt = 0; nt < 4; ++nt) {
            const int row = nt * 16 + l15, sw = row & 7;
            const bf16x8 k0 = *(const bf16x8*)(kcur + row * 64 + ((lg ^ sw) * 8));
            const bf16x8 k1 = *(const bf16x8*)(kcur + row * 64 + (((lg + 4) ^ sw) * 8));
            f32x4 c = (f32x4){0.f, 0.f, 0.f, 0.f};
            c = __builtin_amdgcn_mfma_f32_16x16x32_bf16(k0, aq0, c, 0, 0, 0);
            c = __builtin_amdgcn_mfma_f32_16x16x32_bf16(k1, aq1, c, 0, 0, 0);
            const unsigned bits = (unsigned)(wbits >> (nt * 16 + lg * 4)) & 0xFu;
            #pragma unroll
            for (int r = 0; r < 4; ++r)
                lacc += ((bits >> r) & 1u) ? __expf(c[r] * 0.125f) : 0.f;
        }
        if (kc < 31) {
            *(us8*)(sK[cur ^ 1] + ds0) = nk0;
            *(us8*)(sK[cur ^ 1] + ds1) = nk1;
        }
        BARRIER_LGKM();
    }
    lacc += __shfl_xor(lacc, 16);
    lacc += __shfl_xor(lacc, 32);
    const float inv = 1.0f / lacc;

    {
        const us8 a0 = *(const us8*)(kb + (size_t)t * 8);
        const us8 a1 = *(const us8*)(kb + (size_t)(t + 256) * 8);
        const us8 b0 = *(const us8*)(vb + (size_t)s0row * 2048 + t8 * 8);
        const us8 b1 = *(const us8*)(vb + (size_t)s1row * 2048 + t8 * 8);
        *(us8*)(sK[0] + ds0) = a0;
        *(us8*)(sK[0] + ds1) = a1;
        *(us8*)(sV[0] + ds0) = b0;
        *(us8*)(sV[0] + ds1) = b1;
        BARRIER_LGKM();
    }

    f32x4 o[4];
    #pragma unroll
    for (int nt = 0; nt < 4; ++nt) o[nt] = (f32x4){0.f, 0.f, 0.f, 0.f};

    char* pbw = pbuf[w];
    const int swzP = (l15 & 7) << 4;
    const int ab0 = (l15 * 128 + lg * 16)      ^ swzP;
    const int ab1 = (l15 * 128 + lg * 16 + 64) ^ swzP;

    #pragma unroll 1
    for (int kc = 0; kc < 32; ++kc) {
        const int cur = kc & 1;
        us8 nk0, nk1, nv0, nv1;
        if (kc < 31) {
            const unsigned short* srck = kb + (size_t)(kc + 1) * 4096;
            const unsigned short* srcv = vb + (size_t)(kc + 1) * 64;
            nk0 = *(const us8*)(srck + (size_t)t * 8);
            nk1 = *(const us8*)(srck + (size_t)(t + 256) * 8);
            nv0 = *(const us8*)(srcv + (size_t)s0row * 2048 + t8 * 8);
            nv1 = *(const us8*)(srcv + (size_t)s1row * 2048 + t8 * 8);
        }
        const unsigned long long wbits = ebrow[kc] & ~mb[kc];
        const unsigned short* kcur = sK[cur];
        float4 ev[4];
        #pragma unroll
        for (int nt = 0; nt < 4; ++nt) {
            const int row = nt * 16 + l15, sw = row & 7;
            const bf16x8 k0 = *(const bf16x8*)(kcur + row * 64 + ((lg ^ sw) * 8));
            const bf16x8 k1 = *(const bf16x8*)(kcur + row * 64 + (((lg + 4) ^ sw) * 8));
            f32x4 c = (f32x4){0.f, 0.f, 0.f, 0.f};
            c = __builtin_amdgcn_mfma_f32_16x16x32_bf16(k0, aq0, c, 0, 0, 0);
            c = __builtin_amdgcn_mfma_f32_16x16x32_bf16(k1, aq1, c, 0, 0, 0);
            const unsigned bits = (unsigned)(wbits >> (nt * 16 + lg * 4)) & 0xFu;
            float4 e;
            e.x = (bits & 1u) ? __expf(c[0] * 0.125f) * inv : 0.f;
            e.y = (bits & 2u) ? __expf(c[1] * 0.125f) * inv : 0.f;
            e.z = (bits & 4u) ? __expf(c[2] * 0.125f) * inv : 0.f;
            e.w = (bits & 8u) ? __expf(c[3] * 0.125f) * inv : 0.f;
            ev[nt] = e;
            ushort4 pe;
            pe.x = f2bf(e.x); pe.y = f2bf(e.y); pe.z = f2bf(e.z); pe.w = f2bf(e.w);
            const int wbyte = (l15 * 128 + nt * 32 + lg * 8) ^ swzP;
            *(ushort4*)(pbw + wbyte) = pe;
        }
        const bf16x8 ap0 = *(const bf16x8*)(pbw + ab0);
        const bf16x8 ap1 = *(const bf16x8*)(pbw + ab1);
        const unsigned short* vcur = sV[cur];
        #pragma unroll
        for (int nt = 0; nt < 4; ++nt) {
            const int row = nt * 16 + l15, sw = row & 7;
            const bf16x8 bv0 = *(const bf16x8*)(vcur + row * 64 + ((lg ^ sw) * 8));
            const bf16x8 bv1 = *(const bf16x8*)(vcur + row * 64 + (((lg + 4) ^ sw) * 8));
            o[nt] = __builtin_amdgcn_mfma_f32_16x16x32_bf16(ap0, bv0, o[nt], 0, 0, 0);
            o[nt] = __builtin_amdgcn_mfma_f32_16x16x32_bf16(ap1, bv1, o[nt], 0, 0, 0);
        }
        {
            float* astore = arow + kc * 64;
            #pragma unroll
            for (int nt = 0; nt < 4; ++nt)
                *(float4*)(astore + nt * 16) = ev[nt];
        }
        if (kc < 31) {
            *(us8*)(sK[cur ^ 1] + ds0) = nk0;
            *(us8*)(sK[cur ^ 1] + ds1) = nk1;
            *(us8*)(sV[cur ^ 1] + ds0) = nv0;
            *(us8*)(sV[cur ^ 1] + ds1) = nv1;
        }
        BARRIER_LGKM();
    }

    #pragma unroll
    for (int nt = 0; nt < 4; ++nt)
        #pragma unroll
        for (int r = 0; r < 4; ++r)
            outb[(size_t)(rbase + w * 16 + lg * 4 + r) * D_ + nt * 16 + l15] = o[nt][r];
}

// ================= fp32 deep fallback (needs only 32 KB ws) =================
__global__ __launch_bounds__(256)
void normalize_mask(const void* __restrict__ mask_raw, uint8_t* __restrict__ mask_out)
{
    __shared__ int is_u8;
    const int t = threadIdx.x;
    if (t == 0) is_u8 = 0;
    __syncthreads();
    const int* mi = (const int*)mask_raw;
    int bad = 0;
    for (int i = t; i < 8192; i += 256)
        if ((unsigned)mi[i] > 1u) bad = 1;
    if (bad) atomicOr(&is_u8, 1);
    __syncthreads();
    const int total = BH_ * N_;
    if (is_u8) {
        const uint8_t* m8 = (const uint8_t*)mask_raw;
        for (int i = t; i < total; i += 256) mask_out[i] = m8[i] ? 1 : 0;
    } else {
        for (int i = t; i < total; i += 256) mask_out[i] = (uint8_t)mi[i];
    }
}

__global__ __launch_bounds__(256)
void attn_fused(const float* __restrict__ q, const float* __restrict__ k,
                const float* __restrict__ v, const uint8_t* __restrict__ mask,
                const int* __restrict__ edge, float* __restrict__ out,
                float* __restrict__ attn)
{
    __shared__ float qsT[D_][64 + 4];
    __shared__ float kt [D_][64 + 4];
    __shared__ float vs [64][D_ + 4];
    const int tile = blockIdx.x, bh = blockIdx.y, t = threadIdx.x;
    const int rg = t >> 4, cg = t & 15, r0 = rg * 4, c0 = cg * 4;
    const int row_base = tile * 64;
    const float* qb = q + (size_t)bh * N_ * D_;
    const float* kb = k + (size_t)bh * N_ * D_;
    const float* vb = v + (size_t)bh * N_ * D_;
    const uint8_t* mbp = mask + (size_t)bh * N_;
    const int* ebp = edge + (size_t)(bh & 1) * N_ * N_;
    float* outb = out + (size_t)bh * N_ * D_;
    float* attnb = attn + (size_t)bh * N_ * N_;
    {
        const int rr = t >> 2, dblk = (t & 3) * 16;
        const float* src = qb + (size_t)(row_base + rr) * D_ + dblk;
        #pragma unroll
        for (int qq = 0; qq < 4; ++qq) {
            float4 val = *(const float4*)(src + qq * 4);
            qsT[dblk + qq*4 + 0][rr] = val.x; qsT[dblk + qq*4 + 1][rr] = val.y;
            qsT[dblk + qq*4 + 2][rr] = val.z; qsT[dblk + qq*4 + 3][rr] = val.w;
        }
    }
    float m_i[4], l_i[4];
    #pragma unroll
    for (int i = 0; i < 4; ++i) { m_i[i] = -INFINITY; l_i[i] = 0.f; }
    for (int kc = 0; kc < 32; ++kc) {
        __syncthreads();
        {
            const int ccr = t >> 2, dblk = (t & 3) * 16;
            const float* src = kb + (size_t)(kc * 64 + ccr) * D_ + dblk;
            #pragma unroll
            for (int qq = 0; qq < 4; ++qq) {
                float4 val = *(const float4*)(src + qq * 4);
                kt[dblk + qq*4 + 0][ccr] = val.x; kt[dblk + qq*4 + 1][ccr] = val.y;
                kt[dblk + qq*4 + 2][ccr] = val.z; kt[dblk + qq*4 + 3][ccr] = val.w;
            }
        }
        __syncthreads();
        float sc[4][4];
        #pragma unroll
        for (int i = 0; i < 4; ++i) { sc[i][0]=sc[i][1]=sc[i][2]=sc[i][3]=0.f; }
        for (int d = 0; d < D_; ++d) {
            const float4 qv = *(const float4*)&qsT[d][r0];
            const float4 kv = *(const float4*)&kt[d][c0];
            #pragma unroll
            for (int i = 0; i < 4; ++i) {
                const float qi = (i==0)?qv.x:(i==1)?qv.y:(i==2)?qv.z:qv.w;
                sc[i][0] = fmaf(qi, kv.x, sc[i][0]); sc[i][1] = fmaf(qi, kv.y, sc[i][1]);
                sc[i][2] = fmaf(qi, kv.z, sc[i][2]); sc[i][3] = fmaf(qi, kv.w, sc[i][3]);
            }
        }
        const int cbase = kc * 64 + c0;
        const uint8_t m0 = mbp[cbase], m1 = mbp[cbase+1], m2 = mbp[cbase+2], m3 = mbp[cbase+3];
        #pragma unroll
        for (int i = 0; i < 4; ++i) {
            const int rglob = row_base + r0 + i;
            const int4 e4 = *(const int4*)(ebp + (size_t)rglob * N_ + cbase);
            float s0 = sc[i][0]*0.125f, s1 = sc[i][1]*0.125f, s2 = sc[i][2]*0.125f, s3 = sc[i][3]*0.125f;
            if (e4.x == 0 || m0) s0 = NEGV; if (e4.y == 0 || m1) s1 = NEGV;
            if (e4.z == 0 || m2) s2 = NEGV; if (e4.w == 0 || m3) s3 = NEGV;
            float cmax = fmaxf(fmaxf(s0,s1), fmaxf(s2,s3));
            cmax = fmaxf(cmax, __shfl_xor(cmax,1)); cmax = fmaxf(cmax, __shfl_xor(cmax,2));
            cmax = fmaxf(cmax, __shfl_xor(cmax,4)); cmax = fmaxf(cmax, __shfl_xor(cmax,8));
            const float nm = fmaxf(m_i[i], cmax);
            float ss = __expf(s0-nm)+__expf(s1-nm)+__expf(s2-nm)+__expf(s3-nm);
            ss += __shfl_xor(ss,1); ss += __shfl_xor(ss,2); ss += __shfl_xor(ss,4); ss += __shfl_xor(ss,8);
            l_i[i] = l_i[i]*__expf(m_i[i]-nm) + ss; m_i[i] = nm;
        }
    }
    float inv_l[4];
    #pragma unroll
    for (int i = 0; i < 4; ++i) inv_l[i] = 1.0f / l_i[i];
    float oacc[4][4];
    #pragma unroll
    for (int i = 0; i < 4; ++i) { oacc[i][0]=oacc[i][1]=oacc[i][2]=oacc[i][3]=0.f; }
    for (int kc = 0; kc < 32; ++kc) {
        __syncthreads();
        {
            const int ccr = t >> 2, dblk = (t & 3) * 16;
            const float* src = kb + (size_t)(kc * 64 + ccr) * D_ + dblk;
            #pragma unroll
            for (int qq = 0; qq < 4; ++qq) {
                float4 val = *(const float4*)(src + qq * 4);
                kt[dblk + qq*4 + 0][ccr] = val.x; kt[dblk + qq*4 + 1][ccr] = val.y;
                kt[dblk + qq*4 + 2][ccr] = val.z; kt[dblk + qq*4 + 3][ccr] = val.w;
            }
            const float* srcv = vb + (size_t)(kc * 64 + ccr) * D_ + dblk;
            #pragma unroll
            for (int qq = 0; qq < 4; ++qq)
                *(float4*)&vs[ccr][dblk + qq * 4] = *(const float4*)(srcv + qq * 4);
        }
        __syncthreads();
        float sc[4][4];
        #pragma unroll
        for (int i = 0; i < 4; ++i) { sc[i][0]=sc[i][1]=sc[i][2]=sc[i][3]=0.f; }
        for (int d = 0; d < D_; ++d) {
            const float4 qv = *(const float4*)&qsT[d][r0];
            const float4 kv = *(const float4*)&kt[d][c0];
            #pragma unroll
            for (int i = 0; i < 4; ++i) {
                const float qi = (i==0)?qv.x:(i==1)?qv.y:(i==2)?qv.z:qv.w;
                sc[i][0] = fmaf(qi, kv.x, sc[i][0]); sc[i][1] = fmaf(qi, kv.y, sc[i][1]);
                sc[i][2] = fmaf(qi, kv.z, sc[i][2]); sc[i][3] = fmaf(qi, kv.w, sc[i][3]);
            }
        }
        const int cbase = kc * 64 + c0;
        const uint8_t m0 = mbp[cbase], m1 = mbp[cbase+1], m2 = mbp[cbase+2], m3 = mbp[cbase+3];
        float p[4][4];
        #pragma unroll
        for (int i = 0; i < 4; ++i) {
            const int rglob = row_base + r0 + i;
            const int4 e4 = *(const int4*)(ebp + (size_t)rglob * N_ + cbase);
            float s0 = sc[i][0]*0.125f, s1 = sc[i][1]*0.125f, s2 = sc[i][2]*0.125f, s3 = sc[i][3]*0.125f;
            if (e4.x == 0 || m0) s0 = NEGV; if (e4.y == 0 || m1) s1 = NEGV;
            if (e4.z == 0 || m2) s2 = NEGV; if (e4.w == 0 || m3) s3 = NEGV;
            p[i][0] = __expf(s0-m_i[i])*inv_l[i]; p[i][1] = __expf(s1-m_i[i])*inv_l[i];
            p[i][2] = __expf(s2-m_i[i])*inv_l[i]; p[i][3] = __expf(s3-m_i[i])*inv_l[i];
            *(float4*)&attnb[(size_t)rglob * N_ + cbase] = make_float4(p[i][0],p[i][1],p[i][2],p[i][3]);
        }
        __syncthreads();
        #pragma unroll
        for (int i = 0; i < 4; ++i)
            *(float4*)&kt[r0 + i][c0] = make_float4(p[i][0],p[i][1],p[i][2],p[i][3]);
        __syncthreads();
        for (int c4 = 0; c4 < 64; c4 += 4) {
            float prr[4][4];
            #pragma unroll
            for (int i = 0; i < 4; ++i) {
                const float4 tmp = *(const float4*)&kt[r0 + i][c4];
                prr[i][0]=tmp.x; prr[i][1]=tmp.y; prr[i][2]=tmp.z; prr[i][3]=tmp.w;
            }
            #pragma unroll
            for (int cc = 0; cc < 4; ++cc) {
                const float4 vv = *(const float4*)&vs[c4 + cc][c0];
                #pragma unroll
                for (int i = 0; i < 4; ++i) {
                    oacc[i][0] = fmaf(prr[i][cc], vv.x, oacc[i][0]);
                    oacc[i][1] = fmaf(prr[i][cc], vv.y, oacc[i][1]);
                    oacc[i][2] = fmaf(prr[i][cc], vv.z, oacc[i][2]);
                    oacc[i][3] = fmaf(prr[i][cc], vv.w, oacc[i][3]);
                }
            }
        }
    }
    #pragma unroll
    for (int i = 0; i < 4; ++i)
        *(float4*)&outb[(size_t)(row_base + r0 + i) * D_ + c0] =
            make_float4(oacc[i][0], oacc[i][1], oacc[i][2], oacc[i][3]);
}

extern "C" void kernel_launch(void* const* d_in, const int* in_sizes, int n_in,
                              void* d_out, int out_size, void* d_ws, size_t ws_size,
                              hipStream_t stream) {
    const float* q    = (const float*)d_in[0];
    const float* k    = (const float*)d_in[1];
    const float* v    = (const float*)d_in[2];
    // d_in[3] = k2 (unused by the reference)
    const void*  mraw = d_in[4];
    const int*   edge = (const int*)d_in[5];

    float* out  = (float*)d_out;                         // [16][2048][64]
    float* attn = (float*)d_out + (size_t)BH_ * N_ * D_; // [16][2048][2048]

    char* ws = (char*)d_ws;

    if (ws_size < (size_t)WS_V6) {
        uint8_t* mask_u8 = (uint8_t*)(ws + OFF_MASKU8);
        normalize_mask<<<1, 256, 0, stream>>>(mraw, mask_u8);
        attn_fused<<<dim3(32, 16), 256, 0, stream>>>(q, k, v, mask_u8, edge, out, attn);
        return;
    }

    unsigned long long* mbits = (unsigned long long*)(ws + OFF_MBITS);
    unsigned short*     e16   = (unsigned short*)(ws + OFF_EBITS);
    unsigned short*     qbf   = (unsigned short*)(ws + OFF_QBF);
    unsigned short*     kbf   = (unsigned short*)(ws + OFF_KBF);
    unsigned short*     vT    = (unsigned short*)(ws + OFF_VT);

    prep_all<<<dim3(2576), 256, 0, stream>>>(q, k, v, mraw, edge,
                                             qbf, kbf, vT, e16, mbits);

    if (ws_size >= (size_t)WS_V7) {
        float* psum  = (float*)(ws + OFF_PSUM);
        float* opart = (float*)(ws + OFF_OPART);
        attn_sumk<<<dim3(32, 16, 4), 256, 0, stream>>>(
            qbf, kbf, (const unsigned long long*)e16, mbits, psum);
        attn_pvk<<<dim3(32, 16, 2), 256, 0, stream>>>(
            qbf, kbf, vT, (const unsigned long long*)e16, mbits, psum, opart, attn);
        reduce_o<<<dim3(1024), 256, 0, stream>>>(opart, out);
    } else {
        attn_v6<<<dim3(N_ / 64, BH_), 256, 0, stream>>>(
            qbf, kbf, vT, (const unsigned long long*)e16, mbits, out, attn);
    }
}

// Round 11
// 121.101 us; speedup vs baseline: 1.1229x; 1.1229x over previous
//
#include <hip/hip_runtime.h>
#include <stdint.h>
#include <math.h>

#define BH_ 16
#define N_  2048
#define D_  64
#define NEGV (-1e15f)

typedef __attribute__((ext_vector_type(8))) short bf16x8;
typedef __attribute__((ext_vector_type(8))) unsigned short us8;
typedef __attribute__((ext_vector_type(4))) float f32x4;

// ---------------- workspace layout ----------------
#define OFF_MASKU8 0u
#define OFF_MBITS  32768u                // 16*32 u64
#define OFF_EBITS  65536u                // 2*2048*128 u16 = 1 MB
#define OFF_QBF    1114112u              // 4 MB bf16
#define OFF_KBF    5308416u              // 4 MB
#define OFF_VT     9502720u              // 4 MB (transposed [bh][d][n])
#define WS_V6      13697024u

// Barrier WITHOUT the implicit vmcnt(0) drain of __syncthreads: LDS visibility
// only (lgkmcnt). Global stores/loads stay in flight across it.
#define BARRIER_LGKM() do {                                   \
    asm volatile("s_waitcnt lgkmcnt(0)" ::: "memory");        \
    __builtin_amdgcn_sched_barrier(0);                        \
    __builtin_amdgcn_s_barrier();                             \
    __builtin_amdgcn_sched_barrier(0);                        \
} while (0)

__device__ __forceinline__ unsigned short f2bf(float f) {
    unsigned u = __float_as_uint(f);
    return (unsigned short)((u + 0x7FFFu + ((u >> 16) & 1u)) >> 16);   // RNE
}

// ---- fused prepass: edge pack (blocks 0..2047), q/k/v convert (2048..2559),
//      mask pack+detect (2560..2575)
__global__ __launch_bounds__(256)
void prep_all(const float* __restrict__ q, const float* __restrict__ k,
              const float* __restrict__ v, const void* __restrict__ mraw,
              const int* __restrict__ edge,
              unsigned short* __restrict__ qbf, unsigned short* __restrict__ kbf,
              unsigned short* __restrict__ vT,
              unsigned short* __restrict__ e16, unsigned long long* __restrict__ mbits)
{
    __shared__ unsigned short shbuf[64][72];
    __shared__ int flag;
    const int bid = blockIdx.x;
    const int t   = threadIdx.x;

    if (bid < 2048) {               // ---- edge -> u16 bitmasks (thread-local)
        const int idx = bid * 256 + t;            // 0..524287
        const int4* p = (const int4*)(edge + (size_t)idx * 16);
        unsigned m = 0;
        #pragma unroll
        for (int i = 0; i < 4; ++i) {
            const int4 vv = p[i];
            m |= (vv.x != 0 ? 1u : 0u) << (i * 4 + 0);
            m |= (vv.y != 0 ? 1u : 0u) << (i * 4 + 1);
            m |= (vv.z != 0 ? 1u : 0u) << (i * 4 + 2);
            m |= (vv.w != 0 ? 1u : 0u) << (i * 4 + 3);
        }
        e16[idx] = (unsigned short)m;
    } else if (bid < 2560) {        // ---- q,k -> bf16; v -> bf16 transposed
        const int b2 = bid - 2048;
        const int rt = b2 & 31, bh = b2 >> 5;
        const size_t base = ((size_t)bh * N_ + (size_t)rt * 64) * D_;
        #pragma unroll
        for (int i = 0; i < 4; ++i) {
            const int idx = t + i * 256;
            float4 f = *(const float4*)(q + base + (size_t)idx * 4);
            ushort4 s; s.x = f2bf(f.x); s.y = f2bf(f.y); s.z = f2bf(f.z); s.w = f2bf(f.w);
            *(ushort4*)(qbf + base + (size_t)idx * 4) = s;
            f = *(const float4*)(k + base + (size_t)idx * 4);
            s.x = f2bf(f.x); s.y = f2bf(f.y); s.z = f2bf(f.z); s.w = f2bf(f.w);
            *(ushort4*)(kbf + base + (size_t)idx * 4) = s;
            f = *(const float4*)(v + base + (size_t)idx * 4);
            const int row = idx >> 4;
            const int d0  = (idx & 15) * 4;
            shbuf[d0 + 0][row] = f2bf(f.x);
            shbuf[d0 + 1][row] = f2bf(f.y);
            shbuf[d0 + 2][row] = f2bf(f.z);
            shbuf[d0 + 3][row] = f2bf(f.w);
        }
        __syncthreads();
        const int d  = t >> 2;
        const int c4 = (t & 3) * 16;
        const size_t ob = ((size_t)bh * D_ + d) * N_ + (size_t)rt * 64 + c4;
        *(us8*)(vT + ob)     = *(us8*)&shbuf[d][c4];
        *(us8*)(vT + ob + 8) = *(us8*)&shbuf[d][c4 + 8];
    } else {                        // ---- mask detect + pack
        const int bh = bid - 2560;
        if (t == 0) flag = 0;
        __syncthreads();
        const int* mi = (const int*)mraw;
        int bad = 0;
        for (int i = t; i < 8192; i += 256)
            if ((unsigned)mi[i] > 1u) bad = 1;
        if (bad) atomicOr(&flag, 1);
        __syncthreads();
        const int is_u8 = flag;
        const uint8_t* m8 = (const uint8_t*)mraw;
        const int w4 = t >> 6, l = t & 63;
        for (int it = 0; it < 8; ++it) {
            const int pos = bh * 2048 + it * 256 + w4 * 64 + l;
            const bool on = is_u8 ? (m8[pos] != 0) : (mi[pos] != 0);
            unsigned long long bal = __ballot(on);
            if (l == 0) mbits[bh * 32 + it * 4 + w4] = bal;
        }
    }
}

// ---- main v8 = v6 with XCD-local grid: bh is the FASTEST-varying block dim,
// so XCD = blockId % 8 = bh % 8 -> each XCD serves exactly 2 heads (2 MB K/V,
// fits its 4 MB L2) instead of all 16 (16 MB -> L2 thrash -> L3/HBM latency).
__global__ __launch_bounds__(256)
void attn_v8(const unsigned short* __restrict__ qbf,
             const unsigned short* __restrict__ kbf,
             const unsigned short* __restrict__ vT,
             const unsigned long long* __restrict__ ebits,
             const unsigned long long* __restrict__ mbits,
             float* __restrict__ out, float* __restrict__ attn)
{
    __shared__ unsigned short sK[2][4096];   // 64 keys x 64 d bf16, swizzled 16B slots
    __shared__ unsigned short sV[2][4096];   // 64 d x 64 keys bf16, swizzled
    __shared__ char pbuf[4][2048];           // per-wave 16x64 bf16 P tile

    const int bh   = blockIdx.x;    // FASTEST -> XCD = bh % 8 (T1 locality)
    const int tile = blockIdx.y;    // 0..31
    const int t    = threadIdx.x;
    const int w    = t >> 6;
    const int lane = t & 63;
    const int l15  = lane & 15;
    const int lg   = lane >> 4;
    const int rbase = tile * 64;
    const int myrow = rbase + w * 16 + l15;   // this lane's P/attn row

    const unsigned short* qb = qbf + (size_t)bh * N_ * D_;
    const unsigned short* kb = kbf + (size_t)bh * N_ * D_;
    const unsigned short* vb = vT  + (size_t)bh * D_ * N_;
    const unsigned long long* ebrow =
        ebits + ((size_t)(bh & 1) * N_ + (size_t)myrow) * 32;
    const unsigned long long* mb = mbits + bh * 32;
    float* outb = out + (size_t)bh * N_ * D_;
    float* arow = attn + (size_t)bh * N_ * N_ + (size_t)myrow * N_ + lg * 4;

    // Q fragments (B-operand of swapped QK^T), row = myrow
    const bf16x8 aq0 = *(const bf16x8*)(qb + (size_t)myrow * D_ + lg * 8);
    const bf16x8 aq1 = *(const bf16x8*)(qb + (size_t)myrow * D_ + lg * 8 + 32);

    // cooperative staging: thread t covers 16B slots t and t+256 of each 8KB tile
    const int s0row = t >> 3;               // 0..31
    const int s1row = s0row + 32;           // 32..63
    const int t8    = t & 7;
    const int ds0 = s0row * 64 + ((t8 ^ (s0row & 7)) * 8);
    const int ds1 = s1row * 64 + ((t8 ^ (s1row & 7)) * 8);

    // =============== PASS 1: row sums of exp (K only) ===============
    {
        const us8 a0 = *(const us8*)(kb + (size_t)t * 8);
        const us8 a1 = *(const us8*)(kb + (size_t)(t + 256) * 8);
        *(us8*)(sK[0] + ds0) = a0;
        *(us8*)(sK[0] + ds1) = a1;
        BARRIER_LGKM();
    }
    float lacc = 0.f;
    #pragma unroll 1
    for (int kc = 0; kc < 32; ++kc) {
        const int cur = kc & 1;
        us8 nk0, nk1;
        if (kc < 31) {
            const unsigned short* s = kb + (size_t)(kc + 1) * 4096;
            nk0 = *(const us8*)(s + (size_t)t * 8);
            nk1 = *(const us8*)(s + (size_t)(t + 256) * 8);
        }
        const unsigned long long wbits = ebrow[kc] & ~mb[kc];
        const unsigned short* kcur = sK[cur];
        #pragma unroll
        for (int nt = 0; nt < 4; ++nt) {
            const int row = nt * 16 + l15, sw = row & 7;
            const bf16x8 k0 = *(const bf16x8*)(kcur + row * 64 + ((lg ^ sw) * 8));
            const bf16x8 k1 = *(const bf16x8*)(kcur + row * 64 + (((lg + 4) ^ sw) * 8));
            f32x4 c = (f32x4){0.f, 0.f, 0.f, 0.f};
            c = __builtin_amdgcn_mfma_f32_16x16x32_bf16(k0, aq0, c, 0, 0, 0);
            c = __builtin_amdgcn_mfma_f32_16x16x32_bf16(k1, aq1, c, 0, 0, 0);
            const unsigned bits = (unsigned)(wbits >> (nt * 16 + lg * 4)) & 0xFu;
            #pragma unroll
            for (int r = 0; r < 4; ++r)
                lacc += ((bits >> r) & 1u) ? __expf(c[r] * 0.125f) : 0.f;
        }
        if (kc < 31) {   // write next chunk into the other buffer (its last
                         // readers finished at the kc-1 barrier)
            *(us8*)(sK[cur ^ 1] + ds0) = nk0;
            *(us8*)(sK[cur ^ 1] + ds1) = nk1;
        }
        BARRIER_LGKM();
    }
    lacc += __shfl_xor(lacc, 16);
    lacc += __shfl_xor(lacc, 32);
    const float inv = 1.0f / lacc;     // full row sum (row l15 of wave w's tile)

    // =============== PASS 2: recompute, store attn, PV ===============
    {   // prologue: stage K[0], V[0]  (pass-1 loop ended with a barrier)
        const us8 a0 = *(const us8*)(kb + (size_t)t * 8);
        const us8 a1 = *(const us8*)(kb + (size_t)(t + 256) * 8);
        const us8 b0 = *(const us8*)(vb + (size_t)s0row * 2048 + t8 * 8);
        const us8 b1 = *(const us8*)(vb + (size_t)s1row * 2048 + t8 * 8);
        *(us8*)(sK[0] + ds0) = a0;
        *(us8*)(sK[0] + ds1) = a1;
        *(us8*)(sV[0] + ds0) = b0;
        *(us8*)(sV[0] + ds1) = b1;
        BARRIER_LGKM();
    }

    f32x4 o[4];
    #pragma unroll
    for (int nt = 0; nt < 4; ++nt) o[nt] = (f32x4){0.f, 0.f, 0.f, 0.f};

    char* pbw = pbuf[w];
    const int swzP = (l15 & 7) << 4;
    const int ab0 = (l15 * 128 + lg * 16)      ^ swzP;
    const int ab1 = (l15 * 128 + lg * 16 + 64) ^ swzP;

    #pragma unroll 1
    for (int kc = 0; kc < 32; ++kc) {
        const int cur = kc & 1;
        us8 nk0, nk1, nv0, nv1;
        if (kc < 31) {   // loads issued FIRST (oldest vmem of this chunk)
            const unsigned short* srck = kb + (size_t)(kc + 1) * 4096;
            const unsigned short* srcv = vb + (size_t)(kc + 1) * 64;
            nk0 = *(const us8*)(srck + (size_t)t * 8);
            nk1 = *(const us8*)(srck + (size_t)(t + 256) * 8);
            nv0 = *(const us8*)(srcv + (size_t)s0row * 2048 + t8 * 8);
            nv1 = *(const us8*)(srcv + (size_t)s1row * 2048 + t8 * 8);
        }
        const unsigned long long wbits = ebrow[kc] & ~mb[kc];
        const unsigned short* kcur = sK[cur];
        float4 ev[4];                       // keep attn values for late store
        #pragma unroll
        for (int nt = 0; nt < 4; ++nt) {
            const int row = nt * 16 + l15, sw = row & 7;
            const bf16x8 k0 = *(const bf16x8*)(kcur + row * 64 + ((lg ^ sw) * 8));
            const bf16x8 k1 = *(const bf16x8*)(kcur + row * 64 + (((lg + 4) ^ sw) * 8));
            f32x4 c = (f32x4){0.f, 0.f, 0.f, 0.f};
            c = __builtin_amdgcn_mfma_f32_16x16x32_bf16(k0, aq0, c, 0, 0, 0);
            c = __builtin_amdgcn_mfma_f32_16x16x32_bf16(k1, aq1, c, 0, 0, 0);
            const unsigned bits = (unsigned)(wbits >> (nt * 16 + lg * 4)) & 0xFu;
            float4 e;
            e.x = (bits & 1u) ? __expf(c[0] * 0.125f) * inv : 0.f;
            e.y = (bits & 2u) ? __expf(c[1] * 0.125f) * inv : 0.f;
            e.z = (bits & 4u) ? __expf(c[2] * 0.125f) * inv : 0.f;
            e.w = (bits & 8u) ? __expf(c[3] * 0.125f) * inv : 0.f;
            ev[nt] = e;
            ushort4 pe;
            pe.x = f2bf(e.x); pe.y = f2bf(e.y); pe.z = f2bf(e.z); pe.w = f2bf(e.w);
            const int wbyte = (l15 * 128 + nt * 32 + lg * 8) ^ swzP;  // XOR last
            *(ushort4*)(pbw + wbyte) = pe;             // wave-private P tile
        }
        // PV: own P rows x all d (per-wave in-order DS, no barrier needed)
        const bf16x8 ap0 = *(const bf16x8*)(pbw + ab0);
        const bf16x8 ap1 = *(const bf16x8*)(pbw + ab1);
        const unsigned short* vcur = sV[cur];
        #pragma unroll
        for (int nt = 0; nt < 4; ++nt) {
            const int row = nt * 16 + l15, sw = row & 7;   // d-row
            const bf16x8 bv0 = *(const bf16x8*)(vcur + row * 64 + ((lg ^ sw) * 8));
            const bf16x8 bv1 = *(const bf16x8*)(vcur + row * 64 + (((lg + 4) ^ sw) * 8));
            o[nt] = __builtin_amdgcn_mfma_f32_16x16x32_bf16(ap0, bv0, o[nt], 0, 0, 0);
            o[nt] = __builtin_amdgcn_mfma_f32_16x16x32_bf16(ap1, bv1, o[nt], 0, 0, 0);
        }
        // attn stores LAST (newest vmem): staging's load-wait is counted vmcnt
        // and never drains them; they retire under the next chunk's compute.
        {
            float* astore = arow + kc * 64;
            #pragma unroll
            for (int nt = 0; nt < 4; ++nt)
                *(float4*)(astore + nt * 16) = ev[nt];
        }
        if (kc < 31) {
            *(us8*)(sK[cur ^ 1] + ds0) = nk0;
            *(us8*)(sK[cur ^ 1] + ds1) = nk1;
            *(us8*)(sV[cur ^ 1] + ds0) = nv0;
            *(us8*)(sV[cur ^ 1] + ds1) = nv1;
        }
        BARRIER_LGKM();
    }

    // epilogue: wave w owns rows w*16..w*16+15 completely
    #pragma unroll
    for (int nt = 0; nt < 4; ++nt)
        #pragma unroll
        for (int r = 0; r < 4; ++r)
            outb[(size_t)(rbase + w * 16 + lg * 4 + r) * D_ + nt * 16 + l15] = o[nt][r];
}

// ================= fp32 deep fallback (needs only 32 KB ws) =================
__global__ __launch_bounds__(256)
void normalize_mask(const void* __restrict__ mask_raw, uint8_t* __restrict__ mask_out)
{
    __shared__ int is_u8;
    const int t = threadIdx.x;
    if (t == 0) is_u8 = 0;
    __syncthreads();
    const int* mi = (const int*)mask_raw;
    int bad = 0;
    for (int i = t; i < 8192; i += 256)
        if ((unsigned)mi[i] > 1u) bad = 1;
    if (bad) atomicOr(&is_u8, 1);
    __syncthreads();
    const int total = BH_ * N_;
    if (is_u8) {
        const uint8_t* m8 = (const uint8_t*)mask_raw;
        for (int i = t; i < total; i += 256) mask_out[i] = m8[i] ? 1 : 0;
    } else {
        for (int i = t; i < total; i += 256) mask_out[i] = (uint8_t)mi[i];
    }
}

__global__ __launch_bounds__(256)
void attn_fused(const float* __restrict__ q, const float* __restrict__ k,
                const float* __restrict__ v, const uint8_t* __restrict__ mask,
                const int* __restrict__ edge, float* __restrict__ out,
                float* __restrict__ attn)
{
    __shared__ float qsT[D_][64 + 4];
    __shared__ float kt [D_][64 + 4];
    __shared__ float vs [64][D_ + 4];
    const int tile = blockIdx.x, bh = blockIdx.y, t = threadIdx.x;
    const int rg = t >> 4, cg = t & 15, r0 = rg * 4, c0 = cg * 4;
    const int row_base = tile * 64;
    const float* qb = q + (size_t)bh * N_ * D_;
    const float* kb = k + (size_t)bh * N_ * D_;
    const float* vb = v + (size_t)bh * N_ * D_;
    const uint8_t* mbp = mask + (size_t)bh * N_;
    const int* ebp = edge + (size_t)(bh & 1) * N_ * N_;
    float* outb = out + (size_t)bh * N_ * D_;
    float* attnb = attn + (size_t)bh * N_ * N_;
    {
        const int rr = t >> 2, dblk = (t & 3) * 16;
        const float* src = qb + (size_t)(row_base + rr) * D_ + dblk;
        #pragma unroll
        for (int qq = 0; qq < 4; ++qq) {
            float4 val = *(const float4*)(src + qq * 4);
            qsT[dblk + qq*4 + 0][rr] = val.x; qsT[dblk + qq*4 + 1][rr] = val.y;
            qsT[dblk + qq*4 + 2][rr] = val.z; qsT[dblk + qq*4 + 3][rr] = val.w;
        }
    }
    float m_i[4], l_i[4];
    #pragma unroll
    for (int i = 0; i < 4; ++i) { m_i[i] = -INFINITY; l_i[i] = 0.f; }
    for (int kc = 0; kc < 32; ++kc) {
        __syncthreads();
        {
            const int ccr = t >> 2, dblk = (t & 3) * 16;
            const float* src = kb + (size_t)(kc * 64 + ccr) * D_ + dblk;
            #pragma unroll
            for (int qq = 0; qq < 4; ++qq) {
                float4 val = *(const float4*)(src + qq * 4);
                kt[dblk + qq*4 + 0][ccr] = val.x; kt[dblk + qq*4 + 1][ccr] = val.y;
                kt[dblk + qq*4 + 2][ccr] = val.z; kt[dblk + qq*4 + 3][ccr] = val.w;
            }
        }
        __syncthreads();
        float sc[4][4];
        #pragma unroll
        for (int i = 0; i < 4; ++i) { sc[i][0]=sc[i][1]=sc[i][2]=sc[i][3]=0.f; }
        for (int d = 0; d < D_; ++d) {
            const float4 qv = *(const float4*)&qsT[d][r0];
            const float4 kv = *(const float4*)&kt[d][c0];
            #pragma unroll
            for (int i = 0; i < 4; ++i) {
                const float qi = (i==0)?qv.x:(i==1)?qv.y:(i==2)?qv.z:qv.w;
                sc[i][0] = fmaf(qi, kv.x, sc[i][0]); sc[i][1] = fmaf(qi, kv.y, sc[i][1]);
                sc[i][2] = fmaf(qi, kv.z, sc[i][2]); sc[i][3] = fmaf(qi, kv.w, sc[i][3]);
            }
        }
        const int cbase = kc * 64 + c0;
        const uint8_t m0 = mbp[cbase], m1 = mbp[cbase+1], m2 = mbp[cbase+2], m3 = mbp[cbase+3];
        #pragma unroll
        for (int i = 0; i < 4; ++i) {
            const int rglob = row_base + r0 + i;
            const int4 e4 = *(const int4*)(ebp + (size_t)rglob * N_ + cbase);
            float s0 = sc[i][0]*0.125f, s1 = sc[i][1]*0.125f, s2 = sc[i][2]*0.125f, s3 = sc[i][3]*0.125f;
            if (e4.x == 0 || m0) s0 = NEGV; if (e4.y == 0 || m1) s1 = NEGV;
            if (e4.z == 0 || m2) s2 = NEGV; if (e4.w == 0 || m3) s3 = NEGV;
            float cmax = fmaxf(fmaxf(s0,s1), fmaxf(s2,s3));
            cmax = fmaxf(cmax, __shfl_xor(cmax,1)); cmax = fmaxf(cmax, __shfl_xor(cmax,2));
            cmax = fmaxf(cmax, __shfl_xor(cmax,4)); cmax = fmaxf(cmax, __shfl_xor(cmax,8));
            const float nm = fmaxf(m_i[i], cmax);
            float ss = __expf(s0-nm)+__expf(s1-nm)+__expf(s2-nm)+__expf(s3-nm);
            ss += __shfl_xor(ss,1); ss += __shfl_xor(ss,2); ss += __shfl_xor(ss,4); ss += __shfl_xor(ss,8);
            l_i[i] = l_i[i]*__expf(m_i[i]-nm) + ss; m_i[i] = nm;
        }
    }
    float inv_l[4];
    #pragma unroll
    for (int i = 0; i < 4; ++i) inv_l[i] = 1.0f / l_i[i];
    float oacc[4][4];
    #pragma unroll
    for (int i = 0; i < 4; ++i) { oacc[i][0]=oacc[i][1]=oacc[i][2]=oacc[i][3]=0.f; }
    for (int kc = 0; kc < 32; ++kc) {
        __syncthreads();
        {
            const int ccr = t >> 2, dblk = (t & 3) * 16;
            const float* src = kb + (size_t)(kc * 64 + ccr) * D_ + dblk;
            #pragma unroll
            for (int qq = 0; qq < 4; ++qq) {
                float4 val = *(const float4*)(src + qq * 4);
                kt[dblk + qq*4 + 0][ccr] = val.x; kt[dblk + qq*4 + 1][ccr] = val.y;
                kt[dblk + qq*4 + 2][ccr] = val.z; kt[dblk + qq*4 + 3][ccr] = val.w;
            }
            const float* srcv = vb + (size_t)(kc * 64 + ccr) * D_ + dblk;
            #pragma unroll
            for (int qq = 0; qq < 4; ++qq)
                *(float4*)&vs[ccr][dblk + qq * 4] = *(const float4*)(srcv + qq * 4);
        }
        __syncthreads();
        float sc[4][4];
        #pragma unroll
        for (int i = 0; i < 4; ++i) { sc[i][0]=sc[i][1]=sc[i][2]=sc[i][3]=0.f; }
        for (int d = 0; d < D_; ++d) {
            const float4 qv = *(const float4*)&qsT[d][r0];
            const float4 kv = *(const float4*)&kt[d][c0];
            #pragma unroll
            for (int i = 0; i < 4; ++i) {
                const float qi = (i==0)?qv.x:(i==1)?qv.y:(i==2)?qv.z:qv.w;
                sc[i][0] = fmaf(qi, kv.x, sc[i][0]); sc[i][1] = fmaf(qi, kv.y, sc[i][1]);
                sc[i][2] = fmaf(qi, kv.z, sc[i][2]); sc[i][3] = fmaf(qi, kv.w, sc[i][3]);
            }
        }
        const int cbase = kc * 64 + c0;
        const uint8_t m0 = mbp[cbase], m1 = mbp[cbase+1], m2 = mbp[cbase+2], m3 = mbp[cbase+3];
        float p[4][4];
        #pragma unroll
        for (int i = 0; i < 4; ++i) {
            const int rglob = row_base + r0 + i;
            const int4 e4 = *(const int4*)(ebp + (size_t)rglob * N_ + cbase);
            float s0 = sc[i][0]*0.125f, s1 = sc[i][1]*0.125f, s2 = sc[i][2]*0.125f, s3 = sc[i][3]*0.125f;
            if (e4.x == 0 || m0) s0 = NEGV; if (e4.y == 0 || m1) s1 = NEGV;
            if (e4.z == 0 || m2) s2 = NEGV; if (e4.w == 0 || m3) s3 = NEGV;
            p[i][0] = __expf(s0-m_i[i])*inv_l[i]; p[i][1] = __expf(s1-m_i[i])*inv_l[i];
            p[i][2] = __expf(s2-m_i[i])*inv_l[i]; p[i][3] = __expf(s3-m_i[i])*inv_l[i];
            *(float4*)&attnb[(size_t)rglob * N_ + cbase] = make_float4(p[i][0],p[i][1],p[i][2],p[i][3]);
        }
        __syncthreads();
        #pragma unroll
        for (int i = 0; i < 4; ++i)
            *(float4*)&kt[r0 + i][c0] = make_float4(p[i][0],p[i][1],p[i][2],p[i][3]);
        __syncthreads();
        for (int c4 = 0; c4 < 64; c4 += 4) {
            float prr[4][4];
            #pragma unroll
            for (int i = 0; i < 4; ++i) {
                const float4 tmp = *(const float4*)&kt[r0 + i][c4];
                prr[i][0]=tmp.x; prr[i][1]=tmp.y; prr[i][2]=tmp.z; prr[i][3]=tmp.w;
            }
            #pragma unroll
            for (int cc = 0; cc < 4; ++cc) {
                const float4 vv = *(const float4*)&vs[c4 + cc][c0];
                #pragma unroll
                for (int i = 0; i < 4; ++i) {
                    oacc[i][0] = fmaf(prr[i][cc], vv.x, oacc[i][0]);
                    oacc[i][1] = fmaf(prr[i][cc], vv.y, oacc[i][1]);
                    oacc[i][2] = fmaf(prr[i][cc], vv.z, oacc[i][2]);
                    oacc[i][3] = fmaf(prr[i][cc], vv.w, oacc[i][3]);
                }
            }
        }
    }
    #pragma unroll
    for (int i = 0; i < 4; ++i)
        *(float4*)&outb[(size_t)(row_base + r0 + i) * D_ + c0] =
            make_float4(oacc[i][0], oacc[i][1], oacc[i][2], oacc[i][3]);
}

extern "C" void kernel_launch(void* const* d_in, const int* in_sizes, int n_in,
                              void* d_out, int out_size, void* d_ws, size_t ws_size,
                              hipStream_t stream) {
    const float* q    = (const float*)d_in[0];
    const float* k    = (const float*)d_in[1];
    const float* v    = (const float*)d_in[2];
    // d_in[3] = k2 (unused by the reference)
    const void*  mraw = d_in[4];
    const int*   edge = (const int*)d_in[5];

    float* out  = (float*)d_out;                         // [16][2048][64]
    float* attn = (float*)d_out + (size_t)BH_ * N_ * D_; // [16][2048][2048]

    char* ws = (char*)d_ws;

    if (ws_size < (size_t)WS_V6) {
        uint8_t* mask_u8 = (uint8_t*)(ws + OFF_MASKU8);
        normalize_mask<<<1, 256, 0, stream>>>(mraw, mask_u8);
        attn_fused<<<dim3(32, 16), 256, 0, stream>>>(q, k, v, mask_u8, edge, out, attn);
        return;
    }

    unsigned long long* mbits = (unsigned long long*)(ws + OFF_MBITS);
    unsigned short*     e16   = (unsigned short*)(ws + OFF_EBITS);
    unsigned short*     qbf   = (unsigned short*)(ws + OFF_QBF);
    unsigned short*     kbf   = (unsigned short*)(ws + OFF_KBF);
    unsigned short*     vT    = (unsigned short*)(ws + OFF_VT);

    prep_all<<<dim3(2576), 256, 0, stream>>>(q, k, v, mraw, edge,
                                             qbf, kbf, vT, e16, mbits);
    // bh fastest-varying -> XCD = bh % 8 -> 2 heads per XCD L2 (T1)
    attn_v8<<<dim3(BH_, N_ / 64), 256, 0, stream>>>(
        qbf, kbf, vT, (const unsigned long long*)e16, mbits, out, attn);
}